// Round 4
// baseline (16977.028 us; speedup 1.0000x reference)
//
#include <hip/hip_runtime.h>

typedef unsigned short u16;

#define N_TOK 32768
#define DIM   1280
#define NH    4
#define DH    320
#define FFD   256
#define NLAYER 2
#define NB    64
#define TD    3840  // 3*DIM
#define KVD   2560  // 2*DIM

__device__ __forceinline__ float b2f(u16 v) {
    union { unsigned u; float f; } c; c.u = ((unsigned)v) << 16; return c.f;
}
__device__ __forceinline__ u16 f2b(float f) {
    union { float f; unsigned u; } c; c.f = f;
    unsigned r = c.u + 0x7fffu + ((c.u >> 16) & 1u);
    return (u16)(r >> 16);
}

// ---------------- f32 -> bf16 bulk convert -------------------------------------
__global__ __launch_bounds__(256) void k_f32_to_bf16(
    const float* __restrict__ in, u16* __restrict__ out, long n)
{
    long i = ((long)blockIdx.x * 256 + threadIdx.x) * 4;
    if (i >= n) return;
    float4 v = *(const float4*)&in[i];
    ushort4 o; o.x = f2b(v.x); o.y = f2b(v.y); o.z = f2b(v.z); o.w = f2b(v.w);
    *(ushort4*)&out[i] = o;
}

// ---------------- per-graph offsets via binary search on sorted batch ----------
__global__ void k_offsets(const int* __restrict__ batch, int* __restrict__ offs) {
    int b = threadIdx.x;
    if (b > NB) return;
    int lo = 0, hi = N_TOK;
    while (lo < hi) {
        int mid = (lo + hi) >> 1;
        if (batch[mid] < b) lo = mid + 1; else hi = mid;
    }
    offs[b] = lo;   // offs[64] == N_TOK
}

// ------ GEMM: C[M,Nc] = A_bf16[M,K](lda) @ W_f32[Nc,K]^T + bias
//        store_f32 ? C is float* : C is bf16(u16)*
#define BM 128
#define BN 128
#define BK 16

__global__ __launch_bounds__(256) void k_gemm(
    const u16* __restrict__ A, int lda,
    const float* __restrict__ W,
    const float* __restrict__ bias,
    void* __restrict__ Cv, int ldc,
    int K, int relu, int store_f32)
{
    __shared__ float As[BK][BM + 4];
    __shared__ float Ws[BK][BN + 4];
    const int t  = threadIdx.x;
    const int tx = t & 15, ty = t >> 4;
    const long mBase = (long)blockIdx.y * BM;
    const long nBase = (long)blockIdx.x * BN;
    const int lm = t >> 2;          // 0..63
    const int lk = (t & 3) << 2;    // 0,4,8,12

    float acc[8][8];
    #pragma unroll
    for (int i = 0; i < 8; ++i)
        #pragma unroll
        for (int j = 0; j < 8; ++j) acc[i][j] = 0.f;

    for (int k0 = 0; k0 < K; k0 += BK) {
        ushort4 a0 = *(const ushort4*)&A[(mBase + lm) * (long)lda + k0 + lk];
        ushort4 a1 = *(const ushort4*)&A[(mBase + lm + 64) * (long)lda + k0 + lk];
        float4 w0 = *(const float4*)&W[(nBase + lm) * (long)K + k0 + lk];
        float4 w1 = *(const float4*)&W[(nBase + lm + 64) * (long)K + k0 + lk];
        __syncthreads();
        As[lk + 0][lm] = b2f(a0.x); As[lk + 1][lm] = b2f(a0.y);
        As[lk + 2][lm] = b2f(a0.z); As[lk + 3][lm] = b2f(a0.w);
        As[lk + 0][lm + 64] = b2f(a1.x); As[lk + 1][lm + 64] = b2f(a1.y);
        As[lk + 2][lm + 64] = b2f(a1.z); As[lk + 3][lm + 64] = b2f(a1.w);
        Ws[lk + 0][lm] = w0.x; Ws[lk + 1][lm] = w0.y; Ws[lk + 2][lm] = w0.z; Ws[lk + 3][lm] = w0.w;
        Ws[lk + 0][lm + 64] = w1.x; Ws[lk + 1][lm + 64] = w1.y; Ws[lk + 2][lm + 64] = w1.z; Ws[lk + 3][lm + 64] = w1.w;
        __syncthreads();
        #pragma unroll
        for (int kk = 0; kk < BK; ++kk) {
            float av[8], wv[8];
            *(float4*)&av[0] = *(const float4*)&As[kk][ty * 8];
            *(float4*)&av[4] = *(const float4*)&As[kk][ty * 8 + 4];
            *(float4*)&wv[0] = *(const float4*)&Ws[kk][tx * 8];
            *(float4*)&wv[4] = *(const float4*)&Ws[kk][tx * 8 + 4];
            #pragma unroll
            for (int i = 0; i < 8; ++i)
                #pragma unroll
                for (int j = 0; j < 8; ++j)
                    acc[i][j] = fmaf(av[i], wv[j], acc[i][j]);
        }
    }

    #pragma unroll
    for (int i = 0; i < 8; ++i) {
        long row = mBase + ty * 8 + i;
        #pragma unroll
        for (int j4 = 0; j4 < 8; j4 += 4) {
            long col = nBase + tx * 8 + j4;
            float o[4];
            #pragma unroll
            for (int q = 0; q < 4; ++q) {
                o[q] = acc[i][j4 + q] + bias[col + q];
                if (relu) o[q] = fmaxf(o[q], 0.f);
            }
            if (store_f32) {
                float4 st; st.x = o[0]; st.y = o[1]; st.z = o[2]; st.w = o[3];
                *(float4*)&((float*)Cv)[row * (long)ldc + col] = st;
            } else {
                ushort4 st;
                st.x = f2b(o[0]); st.y = f2b(o[1]); st.z = f2b(o[2]); st.w = f2b(o[3]);
                *(ushort4*)&((u16*)Cv)[row * (long)ldc + col] = st;
            }
        }
    }
}

// --------- fused residual + LayerNorm (bf16 io): out = LN(a + delta)*w + b -----
__global__ __launch_bounds__(256) void k_ln_residual(
    const u16* __restrict__ a, const u16* __restrict__ delta,
    const float* __restrict__ w, const float* __restrict__ bb,
    u16* __restrict__ out)
{
    const long row = blockIdx.x;
    const int t = threadIdx.x;
    float v[5];
    float s = 0.f, s2 = 0.f;
    #pragma unroll
    for (int k = 0; k < 5; ++k) {
        int c = t + (k << 8);
        float xv = b2f(a[row * DIM + c]) + b2f(delta[row * DIM + c]);
        v[k] = xv; s += xv; s2 += xv * xv;
    }
    #pragma unroll
    for (int off = 32; off > 0; off >>= 1) {
        s  += __shfl_down(s, off);
        s2 += __shfl_down(s2, off);
    }
    __shared__ float red[8];
    __shared__ float stat[2];
    const int wid = t >> 6;
    if ((t & 63) == 0) { red[wid] = s; red[wid + 4] = s2; }
    __syncthreads();
    if (t == 0) {
        float S  = red[0] + red[1] + red[2] + red[3];
        float S2 = red[4] + red[5] + red[6] + red[7];
        float mu  = S * (1.f / DIM);
        float var = S2 * (1.f / DIM) - mu * mu;
        stat[0] = mu;
        stat[1] = rsqrtf(fmaxf(var, 0.f) + 1e-5f);
    }
    __syncthreads();
    float mu = stat[0], inv = stat[1];
    #pragma unroll
    for (int k = 0; k < 5; ++k) {
        int c = t + (k << 8);
        out[row * DIM + c] = f2b((v[k] - mu) * inv * w[c] + bb[c]);
    }
}

// -------- flash-style attention (bf16), Q in `q` (ld DIM), K/V in `kv` (ld 2D)
// writes output in-place over q. block=(qtile, head, graph); 256 thr:
// row i = t>>3 (32 rows), chunk jg = t&7 (8 x 40 dims)
__global__ __launch_bounds__(256) void k_attn(
    u16* __restrict__ q, const u16* __restrict__ kv, const int* __restrict__ offs)
{
    __shared__ float KVs[32][324];   // K tile then V tile (time-shared), padded stride
    const int qt = blockIdx.x;
    const int hh = blockIdx.y;
    const int b  = blockIdx.z;
    const int gstart = offs[b];
    const int n = offs[b + 1] - gstart;
    if (qt * 32 >= n) return;
    const int qstart = gstart + qt * 32;
    const int nq = min(32, n - qt * 32);
    const int t  = threadIdx.x;
    const int i  = t >> 3;
    const int jg = t & 7;
    const int dbase = jg * 40;
    const float scale = 0.05590169943749474f;  // 1/sqrt(320)

    float qreg[40];
    const long qrow = (long)(qstart + i) * DIM + hh * DH + dbase;
    if (i < nq) {
        #pragma unroll
        for (int d = 0; d < 40; d += 4) {
            ushort4 qv = *(const ushort4*)&q[qrow + d];
            qreg[d + 0] = b2f(qv.x) * scale; qreg[d + 1] = b2f(qv.y) * scale;
            qreg[d + 2] = b2f(qv.z) * scale; qreg[d + 3] = b2f(qv.w) * scale;
        }
    } else {
        #pragma unroll
        for (int d = 0; d < 40; ++d) qreg[d] = 0.f;
    }
    float oacc[40];
    #pragma unroll
    for (int d = 0; d < 40; ++d) oacc[d] = 0.f;
    float m_i = -1e30f, l_i = 0.f;

    for (int kb = 0; kb < n; kb += 32) {
        const int nk = min(32, n - kb);
        // ---- load K tile ----
        {
            const long krow = (long)(gstart + kb + i) * KVD + hh * DH + dbase;
            if (i < nk) {
                #pragma unroll
                for (int d = 0; d < 40; d += 4) {
                    ushort4 r = *(const ushort4*)&kv[krow + d];
                    float4 f; f.x = b2f(r.x); f.y = b2f(r.y); f.z = b2f(r.z); f.w = b2f(r.w);
                    *(float4*)&KVs[i][dbase + d] = f;
                }
            } else {
                float4 z = make_float4(0.f, 0.f, 0.f, 0.f);
                #pragma unroll
                for (int d = 0; d < 40; d += 4)
                    *(float4*)&KVs[i][dbase + d] = z;
            }
        }
        __syncthreads();
        // ---- scores: sv[j] = q_i . k_j (partial over 40 dims, 8-lane reduce) ----
        float sv[32];
        #pragma unroll
        for (int j = 0; j < 32; ++j) {
            float p0 = 0.f, p1 = 0.f, p2 = 0.f, p3 = 0.f;
            #pragma unroll
            for (int d = 0; d < 40; d += 4) {
                float4 kvv = *(const float4*)&KVs[j][dbase + d];
                p0 = fmaf(qreg[d + 0], kvv.x, p0);
                p1 = fmaf(qreg[d + 1], kvv.y, p1);
                p2 = fmaf(qreg[d + 2], kvv.z, p2);
                p3 = fmaf(qreg[d + 3], kvv.w, p3);
            }
            float sj = (p0 + p1) + (p2 + p3);
            sj += __shfl_xor(sj, 1);
            sj += __shfl_xor(sj, 2);
            sj += __shfl_xor(sj, 4);
            sv[j] = (j < nk) ? sj : -1e30f;
        }
        __syncthreads();   // done reading K tile
        // ---- load V tile over the same LDS ----
        {
            const long vrow = (long)(gstart + kb + i) * KVD + DIM + hh * DH + dbase;
            if (i < nk) {
                #pragma unroll
                for (int d = 0; d < 40; d += 4) {
                    ushort4 r = *(const ushort4*)&kv[vrow + d];
                    float4 f; f.x = b2f(r.x); f.y = b2f(r.y); f.z = b2f(r.z); f.w = b2f(r.w);
                    *(float4*)&KVs[i][dbase + d] = f;
                }
            } else {
                float4 z = make_float4(0.f, 0.f, 0.f, 0.f);
                #pragma unroll
                for (int d = 0; d < 40; d += 4)
                    *(float4*)&KVs[i][dbase + d] = z;
            }
        }
        // ---- online softmax (register-resident; identical across the 8 lanes) ----
        float mx = m_i;
        #pragma unroll
        for (int j = 0; j < 32; ++j) mx = fmaxf(mx, sv[j]);
        float alpha = __expf(m_i - mx);
        float rowsum = 0.f;
        #pragma unroll
        for (int j = 0; j < 32; ++j) { sv[j] = __expf(sv[j] - mx); rowsum += sv[j]; }
        l_i = l_i * alpha + rowsum;
        m_i = mx;
        #pragma unroll
        for (int d = 0; d < 40; ++d) oacc[d] *= alpha;
        __syncthreads();   // V tile ready
        // ---- PV ----
        #pragma unroll
        for (int j = 0; j < 32; ++j) {
            float p = sv[j];
            #pragma unroll
            for (int d = 0; d < 40; d += 4) {
                float4 vv = *(const float4*)&KVs[j][dbase + d];
                oacc[d + 0] = fmaf(p, vv.x, oacc[d + 0]);
                oacc[d + 1] = fmaf(p, vv.y, oacc[d + 1]);
                oacc[d + 2] = fmaf(p, vv.z, oacc[d + 2]);
                oacc[d + 3] = fmaf(p, vv.w, oacc[d + 3]);
            }
        }
        __syncthreads();   // before next K load overwrites LDS
    }
    if (i < nq) {
        float invl = 1.f / l_i;
        #pragma unroll
        for (int d = 0; d < 40; d += 4) {
            ushort4 o;
            o.x = f2b(oacc[d + 0] * invl); o.y = f2b(oacc[d + 1] * invl);
            o.z = f2b(oacc[d + 2] * invl); o.w = f2b(oacc[d + 3] * invl);
            *(ushort4*)&q[qrow + d] = o;   // in-place into q buffer
        }
    }
}

// ---------------- orchestration ------------------------------------------------
extern "C" void kernel_launch(void* const* d_in, const int* in_sizes, int n_in,
                              void* d_out, int out_size, void* d_ws, size_t ws_size,
                              hipStream_t stream) {
    const float* x     = (const float*)d_in[0];
    const int*   batch = (const int*)d_in[1];
    const float* Wqkv  = (const float*)d_in[2];
    const float* bqkv  = (const float*)d_in[3];
    const float* Wo    = (const float*)d_in[4];
    const float* bo    = (const float*)d_in[5];
    const float* ln1w  = (const float*)d_in[6];
    const float* ln1b  = (const float*)d_in[7];
    const float* W1    = (const float*)d_in[8];
    const float* b1    = (const float*)d_in[9];
    const float* W2    = (const float*)d_in[10];
    const float* b2    = (const float*)d_in[11];
    const float* ln2w  = (const float*)d_in[12];
    const float* ln2b  = (const float*)d_in[13];
    const float* Wm1   = (const float*)d_in[14];
    const float* bm1   = (const float*)d_in[15];
    const float* Wm2   = (const float*)d_in[16];
    const float* bm2   = (const float*)d_in[17];

    // d_out: float32, N*D elements (167.8 MB). Its FIRST HALF doubles as the
    // bf16 q/attn-out scratch (84 MB) — dead before the final f32 store.
    float* outF = (float*)d_out;
    u16*   qbuf = (u16*)d_out;

    // compact workspace: 1KB offs + 84MB h + 168MB kv  ~= 240 MiB total
    char* ws  = (char*)d_ws;
    int*  offs = (int*)ws;
    u16*  h    = (u16*)(ws + 1024);               // N*D bf16
    u16*  kvb  = h + (size_t)N_TOK * DIM;         // N*2D bf16 (k|v rows)
    u16*  tmp  = kvb;                             // alias: N*D, live only after attn
    u16*  ff   = kvb + (size_t)N_TOK * DIM;       // alias: N*FF, disjoint from tmp

    k_offsets<<<1, 128, 0, stream>>>(batch, offs);
    {   // h = bf16(x)
        long n = (long)N_TOK * DIM;
        k_f32_to_bf16<<<(int)(n / 4 / 256), 256, 0, stream>>>(x, h, n);
    }

    dim3 blk(256);
    for (int l = 0; l < NLAYER; ++l) {
        const float* Wl = Wqkv + (size_t)l * TD * DIM;
        const float* bl = bqkv + (size_t)l * TD;
        // qbuf = h @ Wq^T + bq       (rows 0..D-1 of Wqkv)
        k_gemm<<<dim3(DIM / BN, N_TOK / BM), blk, 0, stream>>>(
            h, DIM, Wl, bl, qbuf, DIM, DIM, 0, 0);
        // kvb = h @ Wkv^T + bkv      (rows D..3D-1 of Wqkv)
        k_gemm<<<dim3(KVD / BN, N_TOK / BM), blk, 0, stream>>>(
            h, DIM, Wl + (size_t)DIM * DIM, bl + DIM, kvb, KVD, DIM, 0, 0);
        // attention: qbuf <- attn(qbuf, kvb)
        k_attn<<<dim3(20, NH, NB), blk, 0, stream>>>(qbuf, kvb, offs);
        // tmp = qbuf @ Wo^T + bo     (kv dead; tmp aliases it)
        k_gemm<<<dim3(DIM / BN, N_TOK / BM), blk, 0, stream>>>(
            qbuf, DIM, Wo + (size_t)l * DIM * DIM, bo + (size_t)l * DIM,
            tmp, DIM, DIM, 0, 0);
        // h = LN(h + tmp)
        k_ln_residual<<<N_TOK, blk, 0, stream>>>(
            h, tmp, ln1w + (size_t)l * DIM, ln1b + (size_t)l * DIM, h);
        // ff = relu(h @ W1^T + b1)
        k_gemm<<<dim3(FFD / BN, N_TOK / BM), blk, 0, stream>>>(
            h, DIM, W1 + (size_t)l * FFD * DIM, b1 + (size_t)l * FFD,
            ff, FFD, DIM, 1, 0);
        // tmp = ff @ W2^T + b2
        k_gemm<<<dim3(DIM / BN, N_TOK / BM), blk, 0, stream>>>(
            ff, FFD, W2 + (size_t)l * DIM * FFD, b2 + (size_t)l * DIM,
            tmp, DIM, FFD, 0, 0);
        // h = LN(h + tmp)
        k_ln_residual<<<N_TOK, blk, 0, stream>>>(
            h, tmp, ln2w + (size_t)l * DIM, ln2b + (size_t)l * DIM, h);
    }
    // final MLP: ff = relu(h @ Wm1^T + bm1); d_out(f32) = ff @ Wm2^T + bm2
    k_gemm<<<dim3(FFD / BN, N_TOK / BM), blk, 0, stream>>>(
        h, DIM, Wm1, bm1, ff, FFD, DIM, 1, 0);
    k_gemm<<<dim3(DIM / BN, N_TOK / BM), blk, 0, stream>>>(
        ff, FFD, Wm2, bm2, outF, DIM, FFD, 0, 1);
}

// Round 5
// 7682.188 us; speedup vs baseline: 2.2099x; 2.2099x over previous
//
#include <hip/hip_runtime.h>

typedef unsigned short u16;
typedef __attribute__((ext_vector_type(8))) short bf16x8;
typedef __attribute__((ext_vector_type(4))) float f32x4;

#define N_TOK 32768
#define DIM   1280
#define NH    4
#define DH    320
#define FFD   256
#define NLAYER 2
#define NB    64
#define TD    3840  // 3*DIM
#define KVD   2560  // 2*DIM

#define GLD16(gp, lp) __builtin_amdgcn_global_load_lds( \
    (const __attribute__((address_space(1))) unsigned int*)(const void*)(gp), \
    (__attribute__((address_space(3))) unsigned int*)(void*)(lp), 16, 0, 0)

__device__ __forceinline__ float b2f(u16 v) {
    union { unsigned u; float f; } c; c.u = ((unsigned)v) << 16; return c.f;
}
__device__ __forceinline__ u16 f2b(float f) {
    union { float f; unsigned u; } c; c.f = f;
    unsigned r = c.u + 0x7fffu + ((c.u >> 16) & 1u);
    return (u16)(r >> 16);
}

// ---------------- f32 -> bf16 bulk convert -------------------------------------
__global__ __launch_bounds__(256) void k_f32_to_bf16(
    const float* __restrict__ in, u16* __restrict__ out, long n)
{
    long i = ((long)blockIdx.x * 256 + threadIdx.x) * 4;
    if (i >= n) return;
    float4 v = *(const float4*)&in[i];
    ushort4 o; o.x = f2b(v.x); o.y = f2b(v.y); o.z = f2b(v.z); o.w = f2b(v.w);
    *(ushort4*)&out[i] = o;
}

// ---------------- per-graph offsets via binary search on sorted batch ----------
__global__ void k_offsets(const int* __restrict__ batch, int* __restrict__ offs) {
    int b = threadIdx.x;
    if (b > NB) return;
    int lo = 0, hi = N_TOK;
    while (lo < hi) {
        int mid = (lo + hi) >> 1;
        if (batch[mid] < b) lo = mid + 1; else hi = mid;
    }
    offs[b] = lo;   // offs[64] == N_TOK
}

// ------ MFMA GEMM: C[M,N] = A_bf16[M,K](lda) @ W_bf16[N,K]^T + bias_f32
// 128x128 tile, BK=64, 4 waves (each 64x64 = 4x4 frags of 16x16x32 bf16 MFMA).
// m97 structure: global_load_lds width-16 into linear LDS, 2 barriers/K-iter.
__global__ __launch_bounds__(256) void k_gemm_mfma(
    const u16* __restrict__ A, int lda,
    const u16* __restrict__ W,
    const float* __restrict__ bias,
    void* __restrict__ Cv, int ldc,
    int K, int relu, int store_f32)
{
    __shared__ u16 Asm[128 * 64];
    __shared__ u16 Bsm[128 * 64];
    const int t    = threadIdx.x;
    const int lane = t & 63;
    const int w    = t >> 6;           // wave 0..3
    const int wr   = w >> 1, wc = w & 1;
    const long mBase = (long)blockIdx.y * 128;
    const long nBase = (long)blockIdx.x * 128;

    // staging: wave w stages chunks c = w*4+i; chunk c = LDS rows c*8..c*8+7
    // lane writes LDS elems c*512 + lane*8  -> row c*8 + (lane>>3), col (lane&7)*8
    const int srow = lane >> 3;        // 0..7
    const int scol = (lane & 7) * 8;   // 0,8,..,56

    f32x4 acc[4][4];
    #pragma unroll
    for (int m = 0; m < 4; ++m)
        #pragma unroll
        for (int n = 0; n < 4; ++n) acc[m][n] = (f32x4){0.f, 0.f, 0.f, 0.f};

    for (int k0 = 0; k0 < K; k0 += 64) {
        __syncthreads();   // previous iter's ds_reads done before overwrite
        #pragma unroll
        for (int i = 0; i < 4; ++i) {
            const int c = w * 4 + i;
            const u16* ga = &A[(mBase + c * 8 + srow) * (long)lda + k0 + scol];
            const u16* gb = &W[(nBase + c * 8 + srow) * (long)K   + k0 + scol];
            GLD16(ga, &Asm[c * 512]);
            GLD16(gb, &Bsm[c * 512]);
        }
        __syncthreads();   // compiler drains vmcnt(0) before s_barrier
        #pragma unroll
        for (int kk = 0; kk < 2; ++kk) {
            const int kc = kk * 32 + (lane >> 4) * 8;
            bf16x8 af[4], bfr[4];
            #pragma unroll
            for (int m = 0; m < 4; ++m)
                af[m] = *(const bf16x8*)&Asm[(wr * 64 + m * 16 + (lane & 15)) * 64 + kc];
            #pragma unroll
            for (int n = 0; n < 4; ++n)
                bfr[n] = *(const bf16x8*)&Bsm[(wc * 64 + n * 16 + (lane & 15)) * 64 + kc];
            #pragma unroll
            for (int m = 0; m < 4; ++m)
                #pragma unroll
                for (int n = 0; n < 4; ++n)
                    acc[m][n] = __builtin_amdgcn_mfma_f32_16x16x32_bf16(
                        af[m], bfr[n], acc[m][n], 0, 0, 0);
        }
    }

    // epilogue: C/D layout col=lane&15, row=(lane>>4)*4+r  [m89/m91 verified]
    const int ccol  = lane & 15;
    const int crow0 = (lane >> 4) * 4;
    #pragma unroll
    for (int m = 0; m < 4; ++m) {
        #pragma unroll
        for (int n = 0; n < 4; ++n) {
            const long col = nBase + wc * 64 + n * 16 + ccol;
            const float bv = bias[col];
            #pragma unroll
            for (int r = 0; r < 4; ++r) {
                const long row = mBase + wr * 64 + m * 16 + crow0 + r;
                float v = acc[m][n][r] + bv;
                if (relu) v = fmaxf(v, 0.f);
                if (store_f32) ((float*)Cv)[row * (long)ldc + col] = v;
                else           ((u16*)Cv)[row * (long)ldc + col] = f2b(v);
            }
        }
    }
}

// --------- fused residual + LayerNorm (bf16 io): out = LN(a + delta)*w + b -----
__global__ __launch_bounds__(256) void k_ln_residual(
    const u16* __restrict__ a, const u16* __restrict__ delta,
    const float* __restrict__ w, const float* __restrict__ bb,
    u16* __restrict__ out)
{
    const long row = blockIdx.x;
    const int t = threadIdx.x;
    float v[5];
    float s = 0.f, s2 = 0.f;
    #pragma unroll
    for (int k = 0; k < 5; ++k) {
        int c = t + (k << 8);
        float xv = b2f(a[row * DIM + c]) + b2f(delta[row * DIM + c]);
        v[k] = xv; s += xv; s2 += xv * xv;
    }
    #pragma unroll
    for (int off = 32; off > 0; off >>= 1) {
        s  += __shfl_down(s, off);
        s2 += __shfl_down(s2, off);
    }
    __shared__ float red[8];
    __shared__ float stat[2];
    const int wid = t >> 6;
    if ((t & 63) == 0) { red[wid] = s; red[wid + 4] = s2; }
    __syncthreads();
    if (t == 0) {
        float S  = red[0] + red[1] + red[2] + red[3];
        float S2 = red[4] + red[5] + red[6] + red[7];
        float mu  = S * (1.f / DIM);
        float var = S2 * (1.f / DIM) - mu * mu;
        stat[0] = mu;
        stat[1] = rsqrtf(fmaxf(var, 0.f) + 1e-5f);
    }
    __syncthreads();
    float mu = stat[0], inv = stat[1];
    #pragma unroll
    for (int k = 0; k < 5; ++k) {
        int c = t + (k << 8);
        out[row * DIM + c] = f2b((v[k] - mu) * inv * w[c] + bb[c]);
    }
}

// -------- flash-style attention (bf16), Q in `q` (ld DIM), K/V in `kv` (ld 2D)
__global__ __launch_bounds__(256) void k_attn(
    u16* __restrict__ q, const u16* __restrict__ kv, const int* __restrict__ offs)
{
    __shared__ float KVs[32][324];
    const int qt = blockIdx.x;
    const int hh = blockIdx.y;
    const int b  = blockIdx.z;
    const int gstart = offs[b];
    const int n = offs[b + 1] - gstart;
    if (qt * 32 >= n) return;
    const int qstart = gstart + qt * 32;
    const int nq = min(32, n - qt * 32);
    const int t  = threadIdx.x;
    const int i  = t >> 3;
    const int jg = t & 7;
    const int dbase = jg * 40;
    const float scale = 0.05590169943749474f;  // 1/sqrt(320)

    float qreg[40];
    const long qrow = (long)(qstart + i) * DIM + hh * DH + dbase;
    if (i < nq) {
        #pragma unroll
        for (int d = 0; d < 40; d += 4) {
            ushort4 qv = *(const ushort4*)&q[qrow + d];
            qreg[d + 0] = b2f(qv.x) * scale; qreg[d + 1] = b2f(qv.y) * scale;
            qreg[d + 2] = b2f(qv.z) * scale; qreg[d + 3] = b2f(qv.w) * scale;
        }
    } else {
        #pragma unroll
        for (int d = 0; d < 40; ++d) qreg[d] = 0.f;
    }
    float oacc[40];
    #pragma unroll
    for (int d = 0; d < 40; ++d) oacc[d] = 0.f;
    float m_i = -1e30f, l_i = 0.f;

    for (int kb = 0; kb < n; kb += 32) {
        const int nk = min(32, n - kb);
        {
            const long krow = (long)(gstart + kb + i) * KVD + hh * DH + dbase;
            if (i < nk) {
                #pragma unroll
                for (int d = 0; d < 40; d += 4) {
                    ushort4 r = *(const ushort4*)&kv[krow + d];
                    float4 f; f.x = b2f(r.x); f.y = b2f(r.y); f.z = b2f(r.z); f.w = b2f(r.w);
                    *(float4*)&KVs[i][dbase + d] = f;
                }
            } else {
                float4 z = make_float4(0.f, 0.f, 0.f, 0.f);
                #pragma unroll
                for (int d = 0; d < 40; d += 4)
                    *(float4*)&KVs[i][dbase + d] = z;
            }
        }
        __syncthreads();
        float sv[32];
        #pragma unroll
        for (int j = 0; j < 32; ++j) {
            float p0 = 0.f, p1 = 0.f, p2 = 0.f, p3 = 0.f;
            #pragma unroll
            for (int d = 0; d < 40; d += 4) {
                float4 kvv = *(const float4*)&KVs[j][dbase + d];
                p0 = fmaf(qreg[d + 0], kvv.x, p0);
                p1 = fmaf(qreg[d + 1], kvv.y, p1);
                p2 = fmaf(qreg[d + 2], kvv.z, p2);
                p3 = fmaf(qreg[d + 3], kvv.w, p3);
            }
            float sj = (p0 + p1) + (p2 + p3);
            sj += __shfl_xor(sj, 1);
            sj += __shfl_xor(sj, 2);
            sj += __shfl_xor(sj, 4);
            sv[j] = (j < nk) ? sj : -1e30f;
        }
        __syncthreads();
        {
            const long vrow = (long)(gstart + kb + i) * KVD + DIM + hh * DH + dbase;
            if (i < nk) {
                #pragma unroll
                for (int d = 0; d < 40; d += 4) {
                    ushort4 r = *(const ushort4*)&kv[vrow + d];
                    float4 f; f.x = b2f(r.x); f.y = b2f(r.y); f.z = b2f(r.z); f.w = b2f(r.w);
                    *(float4*)&KVs[i][dbase + d] = f;
                }
            } else {
                float4 z = make_float4(0.f, 0.f, 0.f, 0.f);
                #pragma unroll
                for (int d = 0; d < 40; d += 4)
                    *(float4*)&KVs[i][dbase + d] = z;
            }
        }
        float mx = m_i;
        #pragma unroll
        for (int j = 0; j < 32; ++j) mx = fmaxf(mx, sv[j]);
        float alpha = __expf(m_i - mx);
        float rowsum = 0.f;
        #pragma unroll
        for (int j = 0; j < 32; ++j) { sv[j] = __expf(sv[j] - mx); rowsum += sv[j]; }
        l_i = l_i * alpha + rowsum;
        m_i = mx;
        #pragma unroll
        for (int d = 0; d < 40; ++d) oacc[d] *= alpha;
        __syncthreads();
        #pragma unroll
        for (int j = 0; j < 32; ++j) {
            float p = sv[j];
            #pragma unroll
            for (int d = 0; d < 40; d += 4) {
                float4 vv = *(const float4*)&KVs[j][dbase + d];
                oacc[d + 0] = fmaf(p, vv.x, oacc[d + 0]);
                oacc[d + 1] = fmaf(p, vv.y, oacc[d + 1]);
                oacc[d + 2] = fmaf(p, vv.z, oacc[d + 2]);
                oacc[d + 3] = fmaf(p, vv.w, oacc[d + 3]);
            }
        }
        __syncthreads();
    }
    if (i < nq) {
        float invl = 1.f / l_i;
        #pragma unroll
        for (int d = 0; d < 40; d += 4) {
            ushort4 o;
            o.x = f2b(oacc[d + 0] * invl); o.y = f2b(oacc[d + 1] * invl);
            o.z = f2b(oacc[d + 2] * invl); o.w = f2b(oacc[d + 3] * invl);
            *(ushort4*)&q[qrow + d] = o;
        }
    }
}

// ---------------- orchestration ------------------------------------------------
extern "C" void kernel_launch(void* const* d_in, const int* in_sizes, int n_in,
                              void* d_out, int out_size, void* d_ws, size_t ws_size,
                              hipStream_t stream) {
    const float* x     = (const float*)d_in[0];
    const int*   batch = (const int*)d_in[1];
    const float* Wqkv  = (const float*)d_in[2];
    const float* bqkv  = (const float*)d_in[3];
    const float* Wo    = (const float*)d_in[4];
    const float* bo    = (const float*)d_in[5];
    const float* ln1w  = (const float*)d_in[6];
    const float* ln1b  = (const float*)d_in[7];
    const float* W1    = (const float*)d_in[8];
    const float* b1    = (const float*)d_in[9];
    const float* W2    = (const float*)d_in[10];
    const float* b2    = (const float*)d_in[11];
    const float* ln2w  = (const float*)d_in[12];
    const float* ln2b  = (const float*)d_in[13];
    const float* Wm1   = (const float*)d_in[14];
    const float* bm1   = (const float*)d_in[15];
    const float* Wm2   = (const float*)d_in[16];
    const float* bm2   = (const float*)d_in[17];

    float* outF = (float*)d_out;           // f32 output
    u16*   qbuf = (u16*)d_out;             // first half doubles as bf16 q scratch

    // ws: 1KB offs | 84MB h | 168MB kv (tmp/ff alias) | 30MB bf16 weights ~= 282MB
    char* ws   = (char*)d_ws;
    int*  offs = (int*)ws;
    u16*  h    = (u16*)(ws + 1024);
    u16*  kvb  = h + (size_t)N_TOK * DIM;
    u16*  tmp  = kvb;                           // alias, live only after attn
    u16*  ff   = kvb + (size_t)N_TOK * DIM;     // alias, disjoint from tmp
    u16*  wqkv_bf = kvb + (size_t)N_TOK * KVD;  // bf16 weights region
    u16*  wo_bf   = wqkv_bf + (size_t)NLAYER * TD * DIM;
    u16*  w1_bf   = wo_bf   + (size_t)NLAYER * DIM * DIM;
    u16*  w2_bf   = w1_bf   + (size_t)NLAYER * FFD * DIM;
    u16*  wm1_bf  = w2_bf   + (size_t)NLAYER * DIM * FFD;
    u16*  wm2_bf  = wm1_bf  + (size_t)FFD * DIM;

    k_offsets<<<1, 128, 0, stream>>>(batch, offs);
    {   // activations + all weights -> bf16
        long n = (long)N_TOK * DIM;
        k_f32_to_bf16<<<(int)(n / 1024), 256, 0, stream>>>(x, h, n);
        long nqkv = (long)NLAYER * TD * DIM;
        k_f32_to_bf16<<<(int)(nqkv / 1024), 256, 0, stream>>>(Wqkv, wqkv_bf, nqkv);
        long nwo = (long)NLAYER * DIM * DIM;
        k_f32_to_bf16<<<(int)(nwo / 1024), 256, 0, stream>>>(Wo, wo_bf, nwo);
        long nw1 = (long)NLAYER * FFD * DIM;
        k_f32_to_bf16<<<(int)(nw1 / 1024), 256, 0, stream>>>(W1, w1_bf, nw1);
        long nw2 = (long)NLAYER * DIM * FFD;
        k_f32_to_bf16<<<(int)(nw2 / 1024), 256, 0, stream>>>(W2, w2_bf, nw2);
        long nm = (long)FFD * DIM;
        k_f32_to_bf16<<<(int)(nm / 1024), 256, 0, stream>>>(Wm1, wm1_bf, nm);
        k_f32_to_bf16<<<(int)(nm / 1024), 256, 0, stream>>>(Wm2, wm2_bf, nm);
    }

    dim3 blk(256);
    for (int l = 0; l < NLAYER; ++l) {
        const u16*   Wl = wqkv_bf + (size_t)l * TD * DIM;
        const float* bl = bqkv + (size_t)l * TD;
        // qbuf = h @ Wq^T + bq
        k_gemm_mfma<<<dim3(DIM / 128, N_TOK / 128), blk, 0, stream>>>(
            h, DIM, Wl, bl, qbuf, DIM, DIM, 0, 0);
        // kvb = h @ Wkv^T + bkv
        k_gemm_mfma<<<dim3(KVD / 128, N_TOK / 128), blk, 0, stream>>>(
            h, DIM, Wl + (size_t)DIM * DIM, bl + DIM, kvb, KVD, DIM, 0, 0);
        // attention: qbuf <- attn(qbuf, kvb)
        k_attn<<<dim3(20, NH, NB), blk, 0, stream>>>(qbuf, kvb, offs);
        // tmp = qbuf @ Wo^T + bo
        k_gemm_mfma<<<dim3(DIM / 128, N_TOK / 128), blk, 0, stream>>>(
            qbuf, DIM, wo_bf + (size_t)l * DIM * DIM, bo + (size_t)l * DIM,
            tmp, DIM, DIM, 0, 0);
        // h = LN(h + tmp)
        k_ln_residual<<<N_TOK, blk, 0, stream>>>(
            h, tmp, ln1w + (size_t)l * DIM, ln1b + (size_t)l * DIM, h);
        // ff = relu(h @ W1^T + b1)
        k_gemm_mfma<<<dim3(FFD / 128, N_TOK / 128), blk, 0, stream>>>(
            h, DIM, w1_bf + (size_t)l * FFD * DIM, b1 + (size_t)l * FFD,
            ff, FFD, DIM, 1, 0);
        // tmp = ff @ W2^T + b2
        k_gemm_mfma<<<dim3(DIM / 128, N_TOK / 128), blk, 0, stream>>>(
            ff, FFD, w2_bf + (size_t)l * DIM * FFD, b2 + (size_t)l * DIM,
            tmp, DIM, FFD, 0, 0);
        // h = LN(h + tmp)
        k_ln_residual<<<N_TOK, blk, 0, stream>>>(
            h, tmp, ln2w + (size_t)l * DIM, ln2b + (size_t)l * DIM, h);
    }
    // final MLP
    k_gemm_mfma<<<dim3(FFD / 128, N_TOK / 128), blk, 0, stream>>>(
        h, DIM, wm1_bf, bm1, ff, FFD, DIM, 1, 0);
    k_gemm_mfma<<<dim3(DIM / 128, N_TOK / 128), blk, 0, stream>>>(
        ff, FFD, wm2_bf, bm2, outF, DIM, FFD, 0, 1);
}

// Round 6
// 2799.982 us; speedup vs baseline: 6.0633x; 2.7437x over previous
//
#include <hip/hip_runtime.h>

typedef unsigned short u16;
typedef __attribute__((ext_vector_type(8))) short bf16x8;
typedef __attribute__((ext_vector_type(4))) float f32x4;

#define N_TOK 32768
#define DIM   1280
#define NH    4
#define DH    320
#define FFD   256
#define NLAYER 2
#define NB    64
#define TD    3840  // 3*DIM
#define KVD   2560  // 2*DIM

#define GLD16(gp, lp) __builtin_amdgcn_global_load_lds( \
    (const __attribute__((address_space(1))) unsigned int*)(const void*)(gp), \
    (__attribute__((address_space(3))) unsigned int*)(void*)(lp), 16, 0, 0)

__device__ __forceinline__ float b2f(u16 v) {
    union { unsigned u; float f; } c; c.u = ((unsigned)v) << 16; return c.f;
}
__device__ __forceinline__ u16 f2b(float f) {
    union { float f; unsigned u; } c; c.f = f;
    unsigned r = c.u + 0x7fffu + ((c.u >> 16) & 1u);
    return (u16)(r >> 16);
}

// ---------------- f32 -> bf16 bulk convert -------------------------------------
__global__ __launch_bounds__(256) void k_f32_to_bf16(
    const float* __restrict__ in, u16* __restrict__ out, long n)
{
    long i = ((long)blockIdx.x * 256 + threadIdx.x) * 4;
    if (i >= n) return;
    float4 v = *(const float4*)&in[i];
    ushort4 o; o.x = f2b(v.x); o.y = f2b(v.y); o.z = f2b(v.z); o.w = f2b(v.w);
    *(ushort4*)&out[i] = o;
}

// ---------------- per-graph offsets via binary search on sorted batch ----------
__global__ void k_offsets(const int* __restrict__ batch, int* __restrict__ offs) {
    int b = threadIdx.x;
    if (b > NB) return;
    int lo = 0, hi = N_TOK;
    while (lo < hi) {
        int mid = (lo + hi) >> 1;
        if (batch[mid] < b) lo = mid + 1; else hi = mid;
    }
    offs[b] = lo;   // offs[64] == N_TOK
}

// ------ MFMA GEMM: C[M,N] = A_bf16[M,K](lda) @ W_bf16[N,K]^T + bias_f32
__global__ __launch_bounds__(256) void k_gemm_mfma(
    const u16* __restrict__ A, int lda,
    const u16* __restrict__ W,
    const float* __restrict__ bias,
    void* __restrict__ Cv, int ldc,
    int K, int relu, int store_f32)
{
    __shared__ u16 Asm[128 * 64];
    __shared__ u16 Bsm[128 * 64];
    const int t    = threadIdx.x;
    const int lane = t & 63;
    const int w    = t >> 6;
    const int wr   = w >> 1, wc = w & 1;
    const long mBase = (long)blockIdx.y * 128;
    const long nBase = (long)blockIdx.x * 128;
    const int srow = lane >> 3;
    const int scol = (lane & 7) * 8;

    f32x4 acc[4][4];
    #pragma unroll
    for (int m = 0; m < 4; ++m)
        #pragma unroll
        for (int n = 0; n < 4; ++n) acc[m][n] = (f32x4){0.f, 0.f, 0.f, 0.f};

    for (int k0 = 0; k0 < K; k0 += 64) {
        __syncthreads();
        #pragma unroll
        for (int i = 0; i < 4; ++i) {
            const int c = w * 4 + i;
            const u16* ga = &A[(mBase + c * 8 + srow) * (long)lda + k0 + scol];
            const u16* gb = &W[(nBase + c * 8 + srow) * (long)K   + k0 + scol];
            GLD16(ga, &Asm[c * 512]);
            GLD16(gb, &Bsm[c * 512]);
        }
        __syncthreads();
        #pragma unroll
        for (int kk = 0; kk < 2; ++kk) {
            const int kc = kk * 32 + (lane >> 4) * 8;
            bf16x8 af[4], bfr[4];
            #pragma unroll
            for (int m = 0; m < 4; ++m)
                af[m] = *(const bf16x8*)&Asm[(wr * 64 + m * 16 + (lane & 15)) * 64 + kc];
            #pragma unroll
            for (int n = 0; n < 4; ++n)
                bfr[n] = *(const bf16x8*)&Bsm[(wc * 64 + n * 16 + (lane & 15)) * 64 + kc];
            #pragma unroll
            for (int m = 0; m < 4; ++m)
                #pragma unroll
                for (int n = 0; n < 4; ++n)
                    acc[m][n] = __builtin_amdgcn_mfma_f32_16x16x32_bf16(
                        af[m], bfr[n], acc[m][n], 0, 0, 0);
        }
    }

    const int ccol  = lane & 15;
    const int crow0 = (lane >> 4) * 4;
    #pragma unroll
    for (int m = 0; m < 4; ++m) {
        #pragma unroll
        for (int n = 0; n < 4; ++n) {
            const long col = nBase + wc * 64 + n * 16 + ccol;
            const float bv = bias[col];
            #pragma unroll
            for (int r = 0; r < 4; ++r) {
                const long row = mBase + wr * 64 + m * 16 + crow0 + r;
                float v = acc[m][n][r] + bv;
                if (relu) v = fmaxf(v, 0.f);
                if (store_f32) ((float*)Cv)[row * (long)ldc + col] = v;
                else           ((u16*)Cv)[row * (long)ldc + col] = f2b(v);
            }
        }
    }
}

// --------- fused residual + LayerNorm (bf16 io): out = LN(a + delta)*w + b -----
__global__ __launch_bounds__(256) void k_ln_residual(
    const u16* __restrict__ a, const u16* __restrict__ delta,
    const float* __restrict__ w, const float* __restrict__ bb,
    u16* __restrict__ out)
{
    const long row = blockIdx.x;
    const int t = threadIdx.x;
    float v[5];
    float s = 0.f, s2 = 0.f;
    #pragma unroll
    for (int k = 0; k < 5; ++k) {
        int c = t + (k << 8);
        float xv = b2f(a[row * DIM + c]) + b2f(delta[row * DIM + c]);
        v[k] = xv; s += xv; s2 += xv * xv;
    }
    #pragma unroll
    for (int off = 32; off > 0; off >>= 1) {
        s  += __shfl_down(s, off);
        s2 += __shfl_down(s2, off);
    }
    __shared__ float red[8];
    __shared__ float stat[2];
    const int wid = t >> 6;
    if ((t & 63) == 0) { red[wid] = s; red[wid + 4] = s2; }
    __syncthreads();
    if (t == 0) {
        float S  = red[0] + red[1] + red[2] + red[3];
        float S2 = red[4] + red[5] + red[6] + red[7];
        float mu  = S * (1.f / DIM);
        float var = S2 * (1.f / DIM) - mu * mu;
        stat[0] = mu;
        stat[1] = rsqrtf(fmaxf(var, 0.f) + 1e-5f);
    }
    __syncthreads();
    float mu = stat[0], inv = stat[1];
    #pragma unroll
    for (int k = 0; k < 5; ++k) {
        int c = t + (k << 8);
        out[row * DIM + c] = f2b((v[k] - mu) * inv * w[c] + bb[c]);
    }
}

// -------- MFMA flash attention. Q in `q` (ld DIM), K/V in `kv` (ld 2D=KVD).
// block = (qtile32, head, graph), 4 waves. Wave w: S-tile (qr=w>>1, kr=w&1);
// PV: wave w owns output feature slice [w*80, w*80+80).
__global__ __launch_bounds__(256) void k_attn_mfma(
    u16* __restrict__ q, const u16* __restrict__ kv, const int* __restrict__ offs)
{
    __shared__ u16  Ks[32 * 328];     // K tile, pos-major, padded (2-way banks)
    __shared__ u16  Vt[320 * 36];     // V^T tile, feat-major (conflict-free b64)
    __shared__ float Ssm[32 * 32];    // raw scores f32
    __shared__ u16  Plds[32 * 40];    // P bf16, padded
    __shared__ float mL[32], lL[32], aL[32];

    const int qt = blockIdx.x;
    const int hh = blockIdx.y;
    const int b  = blockIdx.z;
    const int gstart = offs[b];
    const int n = offs[b + 1] - gstart;
    if (qt * 32 >= n) return;
    const int nq = min(32, n - qt * 32);
    const int t    = threadIdx.x;
    const int lane = t & 63;
    const int w    = t >> 6;
    const int qr   = w >> 1, kr = w & 1;
    const int l15  = lane & 15;
    const int l4   = lane >> 4;       // 0..3
    const float scale = 0.05590169943749474f;  // 1/sqrt(320)

    if (t < 32) { mL[t] = -1e30f; lL[t] = 0.f; }

    // ---- preload Q fragments (wave's 16 rows, K=320 = 10 chunks) ----
    bf16x8 qf[10];
    {
        int qrl = qt * 32 + qr * 16 + l15;
        if (qrl >= n) qrl = n - 1;    // clamp; rows >= nq never stored
        const u16* gq = &q[(long)(gstart + qrl) * DIM + hh * DH + l4 * 8];
        #pragma unroll
        for (int c = 0; c < 10; ++c)
            qf[c] = *(const bf16x8*)&gq[c * 32];
    }

    f32x4 oacc[2][5];
    #pragma unroll
    for (int a = 0; a < 2; ++a)
        #pragma unroll
        for (int f = 0; f < 5; ++f) oacc[a][f] = (f32x4){0.f, 0.f, 0.f, 0.f};

    __syncthreads();   // stats init visible

    for (int kb = 0; kb < n; kb += 32) {
        const int nk = min(32, n - kb);
        __syncthreads();   // [TOP] prev-iter LDS reads done

        // ---- stage K tile: thread (pos=t>>3, fgroup=t&7 -> 40 feats) ----
        {
            const int pos = t >> 3;
            const int fb  = (t & 7) * 40;
            int gp = kb + pos; if (gp >= n) gp = n - 1;   // content masked later
            const u16* gk = &kv[(long)(gstart + gp) * KVD + hh * DH + fb];
            uint4 c0 = *(const uint4*)(gk + 0);
            uint4 c1 = *(const uint4*)(gk + 8);
            uint4 c2 = *(const uint4*)(gk + 16);
            uint4 c3 = *(const uint4*)(gk + 24);
            uint4 c4 = *(const uint4*)(gk + 32);
            u16* dst = &Ks[pos * 328 + fb];
            *(uint4*)(dst + 0)  = c0;
            *(uint4*)(dst + 8)  = c1;
            *(uint4*)(dst + 16) = c2;
            *(uint4*)(dst + 24) = c3;
            *(uint4*)(dst + 32) = c4;
        }
        // ---- stage V^T: thread (ppair=t&15 -> pos 2p,2p+1; fgroup=t>>4 -> 20 feats)
        {
            const int pp = t & 15;
            const int fb = (t >> 4) * 20;
            int p0 = kb + 2 * pp, p1 = p0 + 1;
            if (p0 >= n) p0 = n - 1;
            if (p1 >= n) p1 = n - 1;
            const u16* g0 = &kv[(long)(gstart + p0) * KVD + DIM + hh * DH + fb];
            const u16* g1 = &kv[(long)(gstart + p1) * KVD + DIM + hh * DH + fb];
            u16 va[20], vb[20];
            #pragma unroll
            for (int i = 0; i < 5; ++i) {
                *(uint2*)&va[i * 4] = *(const uint2*)(g0 + i * 4);
                *(uint2*)&vb[i * 4] = *(const uint2*)(g1 + i * 4);
            }
            #pragma unroll
            for (int f = 0; f < 20; ++f) {
                unsigned pk = (unsigned)va[f] | ((unsigned)vb[f] << 16);
                *(unsigned*)&Vt[(fb + f) * 36 + 2 * pp] = pk;
            }
        }
        __syncthreads();   // [B] tiles staged

        // ---- QK^T: wave computes S-tile (qr, kr), K=320 ----
        {
            f32x4 sacc = (f32x4){0.f, 0.f, 0.f, 0.f};
            #pragma unroll
            for (int c = 0; c < 10; ++c) {
                bf16x8 kf = *(const bf16x8*)&Ks[(kr * 16 + l15) * 328 + c * 32 + l4 * 8];
                sacc = __builtin_amdgcn_mfma_f32_16x16x32_bf16(qf[c], kf, sacc, 0, 0, 0);
            }
            const int col = kr * 16 + l15;
            const int srow0 = qr * 16 + l4 * 4;
            const bool masked = (col >= nk);
            #pragma unroll
            for (int r = 0; r < 4; ++r)
                Ssm[(srow0 + r) * 32 + col] = masked ? -1e30f : sacc[r] * scale;
        }
        __syncthreads();   // [C] scores ready

        // ---- online softmax: row r = t>>3, 8 lanes x 4 cols ----
        {
            const int r  = t >> 3;
            const int cg = (t & 7) * 4;
            float4 s4 = *(const float4*)&Ssm[r * 32 + cg];
            float mx = fmaxf(fmaxf(s4.x, s4.y), fmaxf(s4.z, s4.w));
            mx = fmaxf(mx, __shfl_xor(mx, 1));
            mx = fmaxf(mx, __shfl_xor(mx, 2));
            mx = fmaxf(mx, __shfl_xor(mx, 4));
            const float mo = mL[r];
            const float mn = fmaxf(mo, mx);
            float p0 = __expf(s4.x - mn), p1 = __expf(s4.y - mn);
            float p2 = __expf(s4.z - mn), p3 = __expf(s4.w - mn);
            union { u16 h[4]; uint2 u; } pw;
            pw.h[0] = f2b(p0); pw.h[1] = f2b(p1); pw.h[2] = f2b(p2); pw.h[3] = f2b(p3);
            *(uint2*)&Plds[r * 40 + cg] = pw.u;
            float rs = p0 + p1 + p2 + p3;
            rs += __shfl_xor(rs, 1);
            rs += __shfl_xor(rs, 2);
            rs += __shfl_xor(rs, 4);
            if ((t & 7) == 0) {
                const float al = __expf(mo - mn);
                aL[r] = al;
                lL[r] = lL[r] * al + rs;
                mL[r] = mn;
            }
        }
        __syncthreads();   // [D] P + stats ready

        // ---- PV: rescale O by alpha, then O += P @ V^T (wave's 80 feats) ----
        {
            float al[2][4];
            #pragma unroll
            for (int a = 0; a < 2; ++a)
                #pragma unroll
                for (int r = 0; r < 4; ++r)
                    al[a][r] = aL[a * 16 + l4 * 4 + r];
            #pragma unroll
            for (int a = 0; a < 2; ++a)
                #pragma unroll
                for (int f = 0; f < 5; ++f)
                    #pragma unroll
                    for (int r = 0; r < 4; ++r)
                        oacc[a][f][r] *= al[a][r];
            #pragma unroll
            for (int a = 0; a < 2; ++a) {
                bf16x8 pf = *(const bf16x8*)&Plds[(a * 16 + l15) * 40 + l4 * 8];
                #pragma unroll
                for (int f = 0; f < 5; ++f) {
                    const int fe = w * 80 + f * 16 + l15;
                    union { bf16x8 v; uint2 u[2]; } uv;
                    uv.u[0] = *(const uint2*)&Vt[fe * 36 + l4 * 8];
                    uv.u[1] = *(const uint2*)&Vt[fe * 36 + l4 * 8 + 4];
                    oacc[a][f] = __builtin_amdgcn_mfma_f32_16x16x32_bf16(
                        pf, uv.v, oacc[a][f], 0, 0, 0);
                }
            }
        }
    }

    // ---- epilogue: normalize by 1/l and store wave's feature slice ----
    float invl[2][4];
    #pragma unroll
    for (int a = 0; a < 2; ++a)
        #pragma unroll
        for (int r = 0; r < 4; ++r)
            invl[a][r] = 1.f / lL[a * 16 + l4 * 4 + r];
    #pragma unroll
    for (int a = 0; a < 2; ++a) {
        #pragma unroll
        for (int f = 0; f < 5; ++f) {
            #pragma unroll
            for (int r = 0; r < 4; ++r) {
                const int lrow = a * 16 + l4 * 4 + r;
                if (lrow < nq) {
                    const long grow = (long)(gstart + qt * 32 + lrow);
                    q[grow * DIM + hh * DH + w * 80 + f * 16 + l15] =
                        f2b(oacc[a][f][r] * invl[a][r]);
                }
            }
        }
    }
}

// ---------------- orchestration ------------------------------------------------
extern "C" void kernel_launch(void* const* d_in, const int* in_sizes, int n_in,
                              void* d_out, int out_size, void* d_ws, size_t ws_size,
                              hipStream_t stream) {
    const float* x     = (const float*)d_in[0];
    const int*   batch = (const int*)d_in[1];
    const float* Wqkv  = (const float*)d_in[2];
    const float* bqkv  = (const float*)d_in[3];
    const float* Wo    = (const float*)d_in[4];
    const float* bo    = (const float*)d_in[5];
    const float* ln1w  = (const float*)d_in[6];
    const float* ln1b  = (const float*)d_in[7];
    const float* W1    = (const float*)d_in[8];
    const float* b1    = (const float*)d_in[9];
    const float* W2    = (const float*)d_in[10];
    const float* b2    = (const float*)d_in[11];
    const float* ln2w  = (const float*)d_in[12];
    const float* ln2b  = (const float*)d_in[13];
    const float* Wm1   = (const float*)d_in[14];
    const float* bm1   = (const float*)d_in[15];
    const float* Wm2   = (const float*)d_in[16];
    const float* bm2   = (const float*)d_in[17];

    float* outF = (float*)d_out;
    u16*   qbuf = (u16*)d_out;   // first half doubles as bf16 q scratch

    char* ws   = (char*)d_ws;
    int*  offs = (int*)ws;
    u16*  h    = (u16*)(ws + 1024);
    u16*  kvb  = h + (size_t)N_TOK * DIM;
    u16*  tmp  = kvb;                           // alias, live only after attn
    u16*  ff   = kvb + (size_t)N_TOK * DIM;     // alias, disjoint from tmp
    u16*  wqkv_bf = kvb + (size_t)N_TOK * KVD;
    u16*  wo_bf   = wqkv_bf + (size_t)NLAYER * TD * DIM;
    u16*  w1_bf   = wo_bf   + (size_t)NLAYER * DIM * DIM;
    u16*  w2_bf   = w1_bf   + (size_t)NLAYER * FFD * DIM;
    u16*  wm1_bf  = w2_bf   + (size_t)NLAYER * DIM * FFD;
    u16*  wm2_bf  = wm1_bf  + (size_t)FFD * DIM;

    k_offsets<<<1, 128, 0, stream>>>(batch, offs);
    {
        long n = (long)N_TOK * DIM;
        k_f32_to_bf16<<<(int)(n / 1024), 256, 0, stream>>>(x, h, n);
        long nqkv = (long)NLAYER * TD * DIM;
        k_f32_to_bf16<<<(int)(nqkv / 1024), 256, 0, stream>>>(Wqkv, wqkv_bf, nqkv);
        long nwo = (long)NLAYER * DIM * DIM;
        k_f32_to_bf16<<<(int)(nwo / 1024), 256, 0, stream>>>(Wo, wo_bf, nwo);
        long nw1 = (long)NLAYER * FFD * DIM;
        k_f32_to_bf16<<<(int)(nw1 / 1024), 256, 0, stream>>>(W1, w1_bf, nw1);
        long nw2 = (long)NLAYER * DIM * FFD;
        k_f32_to_bf16<<<(int)(nw2 / 1024), 256, 0, stream>>>(W2, w2_bf, nw2);
        long nm = (long)FFD * DIM;
        k_f32_to_bf16<<<(int)(nm / 1024), 256, 0, stream>>>(Wm1, wm1_bf, nm);
        k_f32_to_bf16<<<(int)(nm / 1024), 256, 0, stream>>>(Wm2, wm2_bf, nm);
    }

    dim3 blk(256);
    for (int l = 0; l < NLAYER; ++l) {
        const u16*   Wl = wqkv_bf + (size_t)l * TD * DIM;
        const float* bl = bqkv + (size_t)l * TD;
        k_gemm_mfma<<<dim3(DIM / 128, N_TOK / 128), blk, 0, stream>>>(
            h, DIM, Wl, bl, qbuf, DIM, DIM, 0, 0);
        k_gemm_mfma<<<dim3(KVD / 128, N_TOK / 128), blk, 0, stream>>>(
            h, DIM, Wl + (size_t)DIM * DIM, bl + DIM, kvb, KVD, DIM, 0, 0);
        k_attn_mfma<<<dim3(20, NH, NB), blk, 0, stream>>>(qbuf, kvb, offs);
        k_gemm_mfma<<<dim3(DIM / 128, N_TOK / 128), blk, 0, stream>>>(
            qbuf, DIM, wo_bf + (size_t)l * DIM * DIM, bo + (size_t)l * DIM,
            tmp, DIM, DIM, 0, 0);
        k_ln_residual<<<N_TOK, blk, 0, stream>>>(
            h, tmp, ln1w + (size_t)l * DIM, ln1b + (size_t)l * DIM, h);
        k_gemm_mfma<<<dim3(FFD / 128, N_TOK / 128), blk, 0, stream>>>(
            h, DIM, w1_bf + (size_t)l * FFD * DIM, b1 + (size_t)l * FFD,
            ff, FFD, DIM, 1, 0);
        k_gemm_mfma<<<dim3(DIM / 128, N_TOK / 128), blk, 0, stream>>>(
            ff, FFD, w2_bf + (size_t)l * DIM * FFD, b2 + (size_t)l * DIM,
            tmp, DIM, FFD, 0, 0);
        k_ln_residual<<<N_TOK, blk, 0, stream>>>(
            h, tmp, ln2w + (size_t)l * DIM, ln2b + (size_t)l * DIM, h);
    }
    k_gemm_mfma<<<dim3(FFD / 128, N_TOK / 128), blk, 0, stream>>>(
        h, DIM, wm1_bf, bm1, ff, FFD, DIM, 1, 0);
    k_gemm_mfma<<<dim3(DIM / 128, N_TOK / 128), blk, 0, stream>>>(
        ff, FFD, wm2_bf, bm2, outF, DIM, FFD, 0, 1);
}